// Round 1
// baseline (333.354 us; speedup 1.0000x reference)
//
#include <hip/hip_runtime.h>

// Problem constants
#define NT 524288          // tokens
#define NE 64              // experts
#define NK 8               // top-k
#define TPB 128            // tokens per block (kernel 1 / 3's granularity)
#define NBLK (NT / TPB)    // 4096 blocks
#define SPB (TPB * NK)     // 1024 slots per block

// ---------------------------------------------------------------------------
// Kernel 1: per-token softmax + top-8 (lax.top_k semantics: descending value,
// ties -> smaller index), logits passthrough, and per-block stable
// arrival-order ranking of slots (packed rank*64+e written to offs region).
// Block = 256 threads = 4 waves. 8 lanes per token, 8 logits per lane.
// ---------------------------------------------------------------------------
__global__ __launch_bounds__(256) void topk_kernel(
    const float* __restrict__ logits,
    float* __restrict__ out_scores,
    float* __restrict__ out_assign,
    float* __restrict__ out_packed,     // offs region, temp: rank*64+e
    float* __restrict__ out_logits,
    int* __restrict__ blockCounts)      // ws: [NBLK][64]
{
    __shared__ int assign_lds[SPB];     // 4 KB
    __shared__ int running[NE];
    __shared__ int wcnt[4][NE];

    const int t = threadIdx.x;
    const int b = blockIdx.x;
    const int g = t & 7;                 // lane within 8-lane token group
    const int tok_in_pass = t >> 3;      // 0..31

    // ---- Phase A: top-k for 128 tokens (4 passes x 32 tokens) ----
    for (int pass = 0; pass < 4; ++pass) {
        const int ltok = pass * 32 + tok_in_pass;       // 0..127
        const int token = b * TPB + ltok;
        const float* lp = logits + (size_t)token * NE + g * 8;
        float4 v0 = *(const float4*)lp;
        float4 v1 = *(const float4*)(lp + 4);
        // passthrough copy
        float* op = out_logits + (size_t)token * NE + g * 8;
        *(float4*)op = v0;
        *(float4*)(op + 4) = v1;

        float l[8] = {v0.x, v0.y, v0.z, v0.w, v1.x, v1.y, v1.z, v1.w};

        // softmax: max over 64 (local 8 + 3-step shuffle within group)
        float m = l[0];
        #pragma unroll
        for (int j = 1; j < 8; ++j) m = fmaxf(m, l[j]);
        #pragma unroll
        for (int sh = 1; sh < 8; sh <<= 1) m = fmaxf(m, __shfl_xor(m, sh, 64));

        float p[8];
        float s = 0.f;
        #pragma unroll
        for (int j = 0; j < 8; ++j) { p[j] = expf(l[j] - m); s += p[j]; }
        #pragma unroll
        for (int sh = 1; sh < 8; sh <<= 1) s += __shfl_xor(s, sh, 64);
        #pragma unroll
        for (int j = 0; j < 8; ++j) p[j] = p[j] / s;   // IEEE div, match ref

        // iterative top-8 on probs; tie -> smaller global index
        float sc = 0.f; int id = 0;
        #pragma unroll
        for (int k = 0; k < NK; ++k) {
            float bv = p[0]; int bi = 0;
            #pragma unroll
            for (int j = 1; j < 8; ++j)
                if (p[j] > bv) { bv = p[j]; bi = j; }   // strict > keeps low idx
            int bidx = g * 8 + bi;
            #pragma unroll
            for (int sh = 1; sh < 8; sh <<= 1) {
                float ov = __shfl_xor(bv, sh, 64);
                int   oi = __shfl_xor(bidx, sh, 64);
                if (ov > bv || (ov == bv && oi < bidx)) { bv = ov; bidx = oi; }
            }
            if (g == k) { sc = bv; id = bidx; }
            if ((bidx >> 3) == g) p[bidx & 7] = -1.0f;  // kill winner
        }

        const size_t slot = (size_t)token * NK + g;     // thread t -> slot, coalesced
        out_scores[slot] = sc;
        out_assign[slot] = (float)id;
        assign_lds[ltok * NK + g] = id;
    }

    // ---- Phase B: stable in-block ranks over 1024 slots ----
    if (t < NE) running[t] = 0;
    __syncthreads();

    const int w = t >> 6;                // wave 0..3
    const int l = t & 63;                // lane
    const unsigned long long lt_mask = (l == 0) ? 0ull : ((~0ull) >> (64 - l));

    for (int tile = 0; tile < 4; ++tile) {
        const int slot_l = tile * 256 + t;              // local slot, in order
        const int e = assign_lds[slot_l];

        // 6-bit radix ballot match: mask of lanes with same expert
        unsigned long long mask = ~0ull;
        #pragma unroll
        for (int bit = 0; bit < 6; ++bit) {
            unsigned long long bb = __ballot((e >> bit) & 1);
            mask &= ((e >> bit) & 1) ? bb : ~bb;
        }
        const int r_in_wave = __popcll(mask & lt_mask);
        const int wc = __popcll(mask);

        wcnt[w][l] = 0;                  // covers all 4x64 entries
        __syncthreads();
        if ((mask & lt_mask) == 0ull) wcnt[w][e] = wc;   // group leader
        __syncthreads();

        int before = running[e];
        for (int w2 = 0; w2 < w; ++w2) before += wcnt[w2][e];
        const int rank = before + r_in_wave;

        const int gslot = b * SPB + slot_l;
        out_packed[gslot] = (float)(rank * 64 + e);      // <= 65535, exact

        __syncthreads();
        if (t < NE) running[t] += wcnt[0][t] + wcnt[1][t] + wcnt[2][t] + wcnt[3][t];
        __syncthreads();
    }

    if (t < NE) blockCounts[b * NE + t] = running[t];
}

// ---------------------------------------------------------------------------
// Kernel 2: per-expert exclusive prefix sum over the 4096 block histograms
// (in place -> block starts). One block per expert. Totals -> counts output.
// ---------------------------------------------------------------------------
__global__ __launch_bounds__(256) void scan_kernel(
    int* __restrict__ blockCounts, float* __restrict__ out_counts)
{
    __shared__ int sdata[256];
    const int e = blockIdx.x;            // 0..63
    const int t = threadIdx.x;           // 0..255
    const int PER = NBLK / 256;          // 16

    int s = 0;
    for (int i = 0; i < PER; ++i) s += blockCounts[(t * PER + i) * NE + e];
    sdata[t] = s;
    __syncthreads();

    // Hillis-Steele inclusive scan over 256 partials
    for (int off = 1; off < 256; off <<= 1) {
        int v = (t >= off) ? sdata[t - off] : 0;
        __syncthreads();
        sdata[t] += v;
        __syncthreads();
    }
    int run = (t == 0) ? 0 : sdata[t - 1];

    for (int i = 0; i < PER; ++i) {
        const int idx = (t * PER + i) * NE + e;
        const int c = blockCounts[idx];
        blockCounts[idx] = run;          // exclusive start for this block
        run += c;
    }
    if (t == 255) out_counts[e] = (float)sdata[255];
}

// ---------------------------------------------------------------------------
// Kernel 3: finalize offsets = blockStart[b][e] + in-block rank (in place).
// ---------------------------------------------------------------------------
__global__ __launch_bounds__(256) void offs_kernel(
    const int* __restrict__ blockCounts, float* __restrict__ out_packed)
{
    __shared__ int base[NE];
    const int b = blockIdx.x;
    const int t = threadIdx.x;
    if (t < NE) base[t] = blockCounts[b * NE + t];
    __syncthreads();
    #pragma unroll
    for (int tile = 0; tile < 4; ++tile) {
        const int gslot = b * SPB + tile * 256 + t;
        const int packed = (int)out_packed[gslot];
        const int e = packed & 63;
        const int rank = packed >> 6;
        out_packed[gslot] = (float)(base[e] + rank);
    }
}

extern "C" void kernel_launch(void* const* d_in, const int* in_sizes, int n_in,
                              void* d_out, int out_size, void* d_ws, size_t ws_size,
                              hipStream_t stream) {
    // inputs: [0] expert_counts placeholder, [1] assignments placeholder,
    //         [2] offsets placeholder, [3] logits [NT, NE] float32
    const float* logits = (const float*)d_in[3];

    float* out = (float*)d_out;
    float* out_counts = out;                                   // [64]
    float* out_scores = out + NE;                              // [NT*NK]
    float* out_assign = out_scores + (size_t)NT * NK;          // [NT*NK]
    float* out_offs   = out_assign + (size_t)NT * NK;          // [NT*NK]
    float* out_logits = out_offs + (size_t)NT * NK;            // [NT*NE]

    int* blockCounts = (int*)d_ws;                             // 4096*64*4 = 1 MB

    hipLaunchKernelGGL(topk_kernel, dim3(NBLK), dim3(256), 0, stream,
                       logits, out_scores, out_assign, out_offs, out_logits,
                       blockCounts);
    hipLaunchKernelGGL(scan_kernel, dim3(NE), dim3(256), 0, stream,
                       blockCounts, out_counts);
    hipLaunchKernelGGL(offs_kernel, dim3(NBLK), dim3(256), 0, stream,
                       blockCounts, out_offs);
}